// Round 2
// baseline (43371.994 us; speedup 1.0000x reference)
//
#include <hip/hip_runtime.h>
#include <math.h>

// B=256, T=256, D=80, H=512, 4H=2048, K=512
#define BB 256
#define TT 256
#define DDIM 80
#define HDIM 512
#define ROWSTRIDE 20480   // T*D

// ws layout (float offsets)
#define WS_HA    0
#define WS_BAR   131072          // 1024 ints (enc: [0..511], dec: [512..1023])
#define WS_HB    132096
#define WS_QUANT 263168
#define WS_VQP   394240
#define WS_BENC  394496
#define WS_BDEC0 396544
#define WS_BEFF  398592
#define WS_WEFF  400640          // 2048*512

__device__ __forceinline__ float sigmoidf_(float v) { return 1.0f / (1.0f + expf(-v)); }

__global__ __launch_bounds__(256) void zero_kernel(float4* __restrict__ p, int n4) {
  int i = blockIdx.x * 256 + threadIdx.x;
  if (i < n4) p[i] = make_float4(0.f, 0.f, 0.f, 0.f);
}

__global__ __launch_bounds__(256) void bias_init_kernel(
    const float* __restrict__ eb1, const float* __restrict__ eb2,
    const float* __restrict__ db1, const float* __restrict__ db2,
    const float* __restrict__ dWih, const float* __restrict__ fcb,
    float* __restrict__ b_enc, float* __restrict__ b_dec0,
    float* __restrict__ b_eff) {
  int n = blockIdx.x * 256 + threadIdx.x;
  b_enc[n] = eb1[n] + eb2[n];
  float bd = db1[n] + db2[n];
  b_dec0[n] = bd;
  float acc = bd;
  #pragma unroll 16
  for (int d = 0; d < DDIM; d++) acc += dWih[n * DDIM + d] * fcb[d];
  b_eff[n] = acc;
}

// W_eff = dec_W_hh + dec_W_ih @ fc_W  (2048x512, K=80)
__global__ __launch_bounds__(256) void fold_kernel(
    const float* __restrict__ dWih, const float* __restrict__ dWhh,
    const float* __restrict__ fcW, float* __restrict__ W_eff) {
  int n = blockIdx.x;
  int tid = threadIdx.x;
  __shared__ float sw[DDIM];
  if (tid < DDIM) sw[tid] = dWih[n * DDIM + tid];
  __syncthreads();
  for (int k = tid; k < HDIM; k += 256) {
    float acc = dWhh[n * HDIM + k];
    #pragma unroll 16
    for (int d = 0; d < DDIM; d++) acc += sw[d] * fcW[d * HDIM + k];
    W_eff[n * HDIM + k] = acc;
  }
}

// ---------------- persistent LSTM: 256 blocks (1/CU), 512 threads ----------------
// Partition: rt = bid&7 (8 row groups x 32 rows), jt = bid>>3 (32 dim groups x 16
// h-dims -> 64 gate rows). W slice LDS-resident across all 256 steps. h ping-pongs
// through global; group barrier = 32-arrival monotonic atomic counter per rt.
// Thread tile: 2 rows (rgrp, rgrp+16) x 2 gates (ggrp, ggrp+32).
__global__ __launch_bounds__(512, 1) void lstm_persistent(
    const int is_dec,
    const float* __restrict__ Wstep0,   // enc: eWhh, dec: dWhh
    const float* __restrict__ Wmain,    // dec: W_eff (staged after t=0)
    const float* __restrict__ Wih,      // enc only [2048][80]
    const float* __restrict__ biasA,    // t==0 bias [2048]
    const float* __restrict__ biasB,    // t>=1 bias [2048]
    const float* __restrict__ traj,     // enc only
    const float* __restrict__ quant,    // dec only [256][512]
    const float* __restrict__ fcW, const float* __restrict__ fcb,
    float* __restrict__ recon,          // dec only [256][256][80]
    float* __restrict__ hA, float* __restrict__ hB,
    int* __restrict__ bar)
{
  __shared__ float W_lds[64][516];   // 132 KB; stride 516: conflict-free f4 reads
  __shared__ float g_lds[32][65];    // gate exchange, pad 65 to spread banks
  __shared__ float c_lds[32][16];    // block-local cell state (never global)

  const int tid = threadIdx.x;
  const int bid = blockIdx.x;
  const int rt = bid & 7, jt = bid >> 3;
  const int r0 = rt * 32, d0 = jt * 16;
  int* cnt = bar + rt * 64;          // 256B-spaced counters

  const int rgrp = tid & 15, ggrp = tid >> 4;  // ggrp 0..31
  // gate id -> global row: g in 0..63, type g>>4 in {i,f,g,o}, dim d0+(g&15)
  const int bidx0 = (ggrp >> 4) * 512 + d0 + (ggrp & 15);        // gate ggrp
  const int bidx1 = (2 + (ggrp >> 4)) * 512 + d0 + (ggrp & 15);  // gate ggrp+32

  // stage step-0 weights: 8 threads per gate row, 16 f4 each
  {
    const int g = tid >> 3, l = tid & 7;
    const int grow = (g >> 4) * 512 + d0 + (g & 15);
    const float4* s4 = (const float4*)(Wstep0 + (size_t)grow * HDIM);
    #pragma unroll
    for (int ii = 0; ii < 16; ii++)
      *(float4*)&W_lds[g][(l + 8 * ii) * 4] = s4[l + 8 * ii];
  }
  c_lds[tid >> 4][tid & 15] = 0.f;
  const float bA0 = biasA[bidx0], bA1 = biasA[bidx1];
  const float bB0 = biasB[bidx0], bB1 = biasB[bidx1];
  __syncthreads();

  const int row0g = r0 + rgrp, row1g = r0 + rgrp + 16;

  for (int t = 0; t < TT; t++) {
    const float* hin;
    float* hout;
    if (t & 1) { hin = hB; hout = hA; }
    else       { hin = (t == 0) ? (is_dec ? quant : hA) : hA; hout = hB; }

    // decoder: y_{t-1} = h_t @ fcW^T + fcb (h_t == hin, published last barrier)
    if (is_dec && t > 0 && jt < 20 && tid < 128) {
      const int yr = tid & 31, dy = tid >> 5;
      const int d = jt * 4 + dy;
      const float4* hv = (const float4*)(hin + (size_t)(r0 + yr) * HDIM);
      const float4* fv = (const float4*)(fcW + (size_t)d * HDIM);
      float acc = fcb[d];
      #pragma unroll 4
      for (int k4 = 0; k4 < 128; k4++) {
        float4 h4 = hv[k4], f4 = fv[k4];
        acc += h4.x * f4.x + h4.y * f4.y + h4.z * f4.z + h4.w * f4.w;
      }
      recon[(size_t)(r0 + yr) * ROWSTRIDE + (size_t)(t - 1) * DDIM + d] = acc;
    }

    // gates = h @ Wslice^T (+ x @ Wih^T for encoder) + bias
    float a00, a01, a10, a11;
    a00 = a10 = (t == 0) ? bA0 : bB0;
    a01 = a11 = (t == 0) ? bA1 : bB1;
    {
      const float4* h0v = (const float4*)(hin + (size_t)row0g * HDIM);
      const float4* h1v = (const float4*)(hin + (size_t)row1g * HDIM);
      const float4* w0v = (const float4*)&W_lds[ggrp][0];
      const float4* w1v = (const float4*)&W_lds[ggrp + 32][0];
      #pragma unroll 4
      for (int k4 = 0; k4 < 128; k4++) {
        float4 h0 = h0v[k4], h1 = h1v[k4];
        float4 w0 = w0v[k4], w1 = w1v[k4];
        a00 += h0.x * w0.x + h0.y * w0.y + h0.z * w0.z + h0.w * w0.w;
        a01 += h0.x * w1.x + h0.y * w1.y + h0.z * w1.z + h0.w * w1.w;
        a10 += h1.x * w0.x + h1.y * w0.y + h1.z * w0.z + h1.w * w0.w;
        a11 += h1.x * w1.x + h1.y * w1.y + h1.z * w1.z + h1.w * w1.w;
      }
    }
    if (!is_dec) {
      const float4* x0v = (const float4*)(traj + (size_t)row0g * ROWSTRIDE + (size_t)t * DDIM);
      const float4* x1v = (const float4*)(traj + (size_t)row1g * ROWSTRIDE + (size_t)t * DDIM);
      const float4* u0v = (const float4*)(Wih + (size_t)bidx0 * DDIM);
      const float4* u1v = (const float4*)(Wih + (size_t)bidx1 * DDIM);
      #pragma unroll
      for (int d4 = 0; d4 < 20; d4++) {
        float4 x0 = x0v[d4], x1 = x1v[d4];
        float4 u0 = u0v[d4], u1 = u1v[d4];
        a00 += x0.x * u0.x + x0.y * u0.y + x0.z * u0.z + x0.w * u0.w;
        a01 += x0.x * u1.x + x0.y * u1.y + x0.z * u1.z + x0.w * u1.w;
        a10 += x1.x * u0.x + x1.y * u0.y + x1.z * u0.z + x1.w * u0.w;
        a11 += x1.x * u1.x + x1.y * u1.y + x1.z * u1.z + x1.w * u1.w;
      }
    }

    // exchange gates within block, fused LSTM elementwise
    g_lds[rgrp][ggrp] = a00;
    g_lds[rgrp][ggrp + 32] = a01;
    g_lds[rgrp + 16][ggrp] = a10;
    g_lds[rgrp + 16][ggrp + 32] = a11;
    __syncthreads();
    {
      const int row = tid >> 4, dd = tid & 15;
      float ig = g_lds[row][dd],      fg = g_lds[row][16 + dd];
      float gg = g_lds[row][32 + dd], og = g_lds[row][48 + dd];
      float cv = c_lds[row][dd];
      float cn = sigmoidf_(fg) * cv + sigmoidf_(ig) * tanhf(gg);
      float hn = sigmoidf_(og) * tanhf(cn);
      c_lds[row][dd] = cn;
      hout[(size_t)(r0 + row) * HDIM + d0 + dd] = hn;
    }

    // group barrier (32 blocks of this rt), release/acquire on h buffers
    __syncthreads();
    if (tid == 0) {
      __threadfence();
      __hip_atomic_fetch_add(cnt, 1, __ATOMIC_RELEASE, __HIP_MEMORY_SCOPE_AGENT);
      const int target = 32 * (t + 1);
      while (__hip_atomic_load(cnt, __ATOMIC_ACQUIRE, __HIP_MEMORY_SCOPE_AGENT) < target)
        __builtin_amdgcn_s_sleep(1);
      __threadfence();
    }
    __syncthreads();

    // decoder: swap in folded weights after step 0
    if (is_dec && t == 0) {
      const int g = tid >> 3, l = tid & 7;
      const int grow = (g >> 4) * 512 + d0 + (g & 15);
      const float4* s4 = (const float4*)(Wmain + (size_t)grow * HDIM);
      #pragma unroll
      for (int ii = 0; ii < 16; ii++)
        *(float4*)&W_lds[g][(l + 8 * ii) * 4] = s4[l + 8 * ii];
      __syncthreads();
    }
  }

  // decoder: final y (col 255) from h_256 = hA (255 odd -> wrote hA)
  if (is_dec && jt < 20 && tid < 128) {
    const int yr = tid & 31, dy = tid >> 5;
    const int d = jt * 4 + dy;
    const float4* hv = (const float4*)(hA + (size_t)(r0 + yr) * HDIM);
    const float4* fv = (const float4*)(fcW + (size_t)d * HDIM);
    float acc = fcb[d];
    #pragma unroll 4
    for (int k4 = 0; k4 < 128; k4++) {
      float4 h4 = hv[k4], f4 = fv[k4];
      acc += h4.x * f4.x + h4.y * f4.y + h4.z * f4.z + h4.w * f4.w;
    }
    recon[(size_t)(r0 + yr) * ROWSTRIDE + (size_t)255 * DDIM + d] = acc;
  }
}

// ---------------- vector quantizer: argmin_k ||e_k||^2 - 2 z.e_k -----------------
__global__ __launch_bounds__(256) void vq_kernel(
    const float* __restrict__ z, const float* __restrict__ emb,
    float* __restrict__ quant, float* __restrict__ vq_part,
    float* __restrict__ out_idx) {
  __shared__ float sz[512];
  __shared__ float sd[256];
  __shared__ int si[256];
  int b = blockIdx.x, tid = threadIdx.x;
  sz[tid] = z[(size_t)b * HDIM + tid];
  sz[tid + 256] = z[(size_t)b * HDIM + 256 + tid];
  __syncthreads();
  float bd = 3.4e38f;
  int bk = 0;
  for (int k = tid; k < 512; k += 256) {
    const float4* e4 = (const float4*)(emb + (size_t)k * HDIM);
    const float4* z4 = (const float4*)sz;
    float dot = 0.f, ee = 0.f;
    #pragma unroll 4
    for (int q = 0; q < 128; q++) {
      float4 ev = e4[q], zv = z4[q];
      dot += ev.x * zv.x + ev.y * zv.y + ev.z * zv.z + ev.w * zv.w;
      ee += ev.x * ev.x + ev.y * ev.y + ev.z * ev.z + ev.w * ev.w;
    }
    float dist = ee - 2.f * dot;
    if (dist < bd) { bd = dist; bk = k; }
  }
  sd[tid] = bd; si[tid] = bk;
  __syncthreads();
  for (int s = 128; s > 0; s >>= 1) {
    if (tid < s) {
      float od = sd[tid + s]; int ok = si[tid + s];
      if (od < sd[tid] || (od == sd[tid] && ok < si[tid])) { sd[tid] = od; si[tid] = ok; }
    }
    __syncthreads();
  }
  int kbest = si[0];
  __syncthreads();
  float e0 = emb[(size_t)kbest * HDIM + tid];
  float e1 = emb[(size_t)kbest * HDIM + 256 + tid];
  quant[(size_t)b * HDIM + tid] = e0;
  quant[(size_t)b * HDIM + 256 + tid] = e1;
  float q0 = e0 - sz[tid], q1 = e1 - sz[tid + 256];
  sd[tid] = q0 * q0 + q1 * q1;
  __syncthreads();
  for (int st = 128; st > 0; st >>= 1) {
    if (tid < st) sd[tid] += sd[tid + st];
    __syncthreads();
  }
  if (tid == 0) { vq_part[b] = sd[0]; out_idx[b] = (float)kbest; }
}

__global__ __launch_bounds__(256) void vq_reduce_kernel(const float* __restrict__ vq_part,
                                                        float* __restrict__ out_loss) {
  __shared__ float s[256];
  int tid = threadIdx.x;
  s[tid] = vq_part[tid];
  __syncthreads();
  for (int st = 128; st > 0; st >>= 1) {
    if (tid < st) s[tid] += s[tid + st];
    __syncthreads();
  }
  if (tid == 0) out_loss[0] = s[0] * 1.25f / (float)(BB * HDIM);
}

extern "C" void kernel_launch(void* const* d_in, const int* in_sizes, int n_in,
                              void* d_out, int out_size, void* d_ws, size_t ws_size,
                              hipStream_t stream) {
  const float* traj = (const float*)d_in[0];
  const float* eWih = (const float*)d_in[2];
  const float* eWhh = (const float*)d_in[3];
  const float* eb1  = (const float*)d_in[4];
  const float* eb2  = (const float*)d_in[5];
  const float* emb  = (const float*)d_in[6];
  const float* dWih = (const float*)d_in[7];
  const float* dWhh = (const float*)d_in[8];
  const float* db1  = (const float*)d_in[9];
  const float* db2  = (const float*)d_in[10];
  const float* fcW  = (const float*)d_in[11];
  const float* fcb  = (const float*)d_in[12];

  float* out = (float*)d_out;
  float* recon = out;                 // [256][256][80]
  float* out_loss = out + 5242880;
  float* out_idx = out + 5242881;

  float* ws = (float*)d_ws;
  float* hA      = ws + WS_HA;
  int*   bar     = (int*)(ws + WS_BAR);
  float* hB      = ws + WS_HB;
  float* quant   = ws + WS_QUANT;
  float* vq_part = ws + WS_VQP;
  float* b_enc   = ws + WS_BENC;
  float* b_dec0  = ws + WS_BDEC0;
  float* b_eff   = ws + WS_BEFF;
  float* W_eff   = ws + WS_WEFF;

  // zero h0 + barrier counters (132096 floats = 33024 float4)
  zero_kernel<<<129, 256, 0, stream>>>((float4*)ws, 33024);
  bias_init_kernel<<<8, 256, 0, stream>>>(eb1, eb2, db1, db2, dWih, fcb,
                                          b_enc, b_dec0, b_eff);
  fold_kernel<<<2048, 256, 0, stream>>>(dWih, dWhh, fcW, W_eff);

  // encoder: 256 steps in one persistent kernel; z lands in hA
  lstm_persistent<<<256, 512, 0, stream>>>(
      0, eWhh, eWhh, eWih, b_enc, b_enc, traj,
      nullptr, nullptr, nullptr, nullptr, hA, hB, bar);

  vq_kernel<<<256, 256, 0, stream>>>(hA, emb, quant, vq_part, out_idx);
  vq_reduce_kernel<<<1, 256, 0, stream>>>(vq_part, out_loss);

  // decoder: 256 steps + fused y outputs
  lstm_persistent<<<256, 512, 0, stream>>>(
      1, dWhh, W_eff, nullptr, b_dec0, b_eff, nullptr,
      quant, fcW, fcb, recon, hA, hB, bar + 512);
}

// Round 3
// 23790.973 us; speedup vs baseline: 1.8230x; 1.8230x over previous
//
#include <hip/hip_runtime.h>
#include <math.h>

// B=256, T=256, D=80, H=512, 4H=2048, K=512
#define BB 256
#define TT 256
#define DDIM 80
#define HDIM 512
#define ROWSTRIDE 20480   // T*D

// ws layout (float offsets)
#define WS_HA    0          // 131072 (zeroed: enc h0 / final z)
#define WS_CD    131072     // 131072 (zeroed: dec cell state)
#define WS_BAR   262144     // 1024 ints (zeroed)
#define WS_HB    263168     // 131072
#define WS_QUANT 394240     // 131072
#define WS_VQP   525312     // 256
#define WS_BENC  525568     // 2048
#define WS_BDEC0 527616     // 2048
#define WS_BEFF  529664     // 2048
#define WS_WEFF  531712     // 1048576 -> total 1580288 floats (~6.1 MB)

__device__ __forceinline__ float sigmoidf_(float v) { return 1.0f / (1.0f + expf(-v)); }

__global__ __launch_bounds__(256) void zero_kernel(float4* __restrict__ p, int n4) {
  int i = blockIdx.x * 256 + threadIdx.x;
  if (i < n4) p[i] = make_float4(0.f, 0.f, 0.f, 0.f);
}

__global__ __launch_bounds__(256) void bias_init_kernel(
    const float* __restrict__ eb1, const float* __restrict__ eb2,
    const float* __restrict__ db1, const float* __restrict__ db2,
    const float* __restrict__ dWih, const float* __restrict__ fcb,
    float* __restrict__ b_enc, float* __restrict__ b_dec0,
    float* __restrict__ b_eff) {
  int n = blockIdx.x * 256 + threadIdx.x;
  b_enc[n] = eb1[n] + eb2[n];
  float bd = db1[n] + db2[n];
  b_dec0[n] = bd;
  float acc = bd;
  #pragma unroll 16
  for (int d = 0; d < DDIM; d++) acc += dWih[n * DDIM + d] * fcb[d];
  b_eff[n] = acc;
}

// W_eff = dec_W_hh + dec_W_ih @ fc_W  (2048x512, K=80)
__global__ __launch_bounds__(256) void fold_kernel(
    const float* __restrict__ dWih, const float* __restrict__ dWhh,
    const float* __restrict__ fcW, float* __restrict__ W_eff) {
  int n = blockIdx.x;
  int tid = threadIdx.x;
  __shared__ float sw[DDIM];
  if (tid < DDIM) sw[tid] = dWih[n * DDIM + tid];
  __syncthreads();
  for (int k = tid; k < HDIM; k += 256) {
    float acc = dWhh[n * HDIM + k];
    #pragma unroll 16
    for (int d = 0; d < DDIM; d++) acc += sw[d] * fcW[d * HDIM + k];
    W_eff[n * HDIM + k] = acc;
  }
}

// ---------------- round-1 single LSTM step (used once: decoder t=0) --------------
__global__ __launch_bounds__(256) void lstm_step_kernel(
    const float* __restrict__ x, const float* __restrict__ Wih,
    const float* __restrict__ Whh, const float* __restrict__ bias,
    const float* __restrict__ h_in, float* __restrict__ c,
    float* __restrict__ h_out) {
  __shared__ float sh[16][516];
  int tid = threadIdx.x;
  int rt = blockIdx.x & 15, jt = blockIdx.x >> 4;
  int row0 = rt << 4;
  for (int i = tid; i < 2048; i += 256) {
    int r = i >> 7, kq = i & 127;
    float4 v = *(const float4*)(h_in + (size_t)(row0 + r) * HDIM + (kq << 2));
    *(float4*)&sh[r][kq << 2] = v;
  }
  __syncthreads();
  int r = tid & 15, j0 = tid >> 4;
  int j = (jt << 4) + j0;
  float a0 = bias[j], a1 = bias[512 + j], a2 = bias[1024 + j], a3 = bias[1536 + j];
  const float4* w0 = (const float4*)(Whh + (size_t)j * HDIM);
  const float4* w1 = (const float4*)(Whh + (size_t)(512 + j) * HDIM);
  const float4* w2 = (const float4*)(Whh + (size_t)(1024 + j) * HDIM);
  const float4* w3 = (const float4*)(Whh + (size_t)(1536 + j) * HDIM);
  const float4* hv = (const float4*)&sh[r][0];
  #pragma unroll 4
  for (int kq = 0; kq < 128; kq++) {
    float4 h4 = hv[kq];
    float4 q0 = w0[kq], q1 = w1[kq], q2 = w2[kq], q3 = w3[kq];
    a0 += h4.x * q0.x + h4.y * q0.y + h4.z * q0.z + h4.w * q0.w;
    a1 += h4.x * q1.x + h4.y * q1.y + h4.z * q1.z + h4.w * q1.w;
    a2 += h4.x * q2.x + h4.y * q2.y + h4.z * q2.z + h4.w * q2.w;
    a3 += h4.x * q3.x + h4.y * q3.y + h4.z * q3.z + h4.w * q3.w;
  }
  size_t idx = (size_t)(row0 + r) * HDIM + j;
  float cv = c[idx];
  float cn = sigmoidf_(a1) * cv + sigmoidf_(a0) * tanhf(a2);
  float hn = sigmoidf_(a3) * tanhf(cn);
  c[idx] = cn;
  h_out[idx] = hn;
}

// ---------------- persistent register-stationary LSTM ----------------------------
// 256 blocks (1/CU, 91 KB LDS), 512 threads. Block (rt=bid&7, jt=bid>>3):
// rows [rt*32,+32), h-dims [jt*16,+16) -> 64 gate rows. Wave w (of 8) owns
// k-chunk [w*64,+64); lane = gate row; W slice in 64 VGPRs for all 256 steps.
// h[b][kchunk] is wave-uniform -> scalar loads; partials reduced via LDS;
// c in one VGPR/thread. Group barrier = 32-arrival atomic counter per rt.
template <int IS_DEC>
__global__ __launch_bounds__(512, 2) void lstm_persist(
    const float* __restrict__ W,      // enc: eWhh; dec: W_eff  [2048][512]
    const float* __restrict__ Wih,    // enc only [2048][80]
    const float* __restrict__ bias,   // enc: b_enc; dec: b_eff [2048]
    const float* __restrict__ traj,   // enc only
    const float* __restrict__ c_init, // dec: cD (holds c_1)
    const float* __restrict__ fcW, const float* __restrict__ fcb,
    float* __restrict__ recon,
    float* __restrict__ hA, float* __restrict__ hB,
    int* __restrict__ bar) {
  __shared__ float partials[8 * 2052];   // [wave][b*64+gate], pad stride 2052
  __shared__ float reduced[2048];        // [b][gate]
  __shared__ float sbias[64];
  __shared__ float fcw_lds[4][512];      // dec y-slice (jt<20)
  __shared__ float ypart[32 * 68];       // [r][f4*4+d], stride 68

  const int tid = threadIdx.x;
  const int bid = blockIdx.x;
  const int rt = bid & 7, jt = bid >> 3;
  const int r0 = rt * 32, d0 = jt * 16;
  int* cnt = bar + rt * 64;

  const int lane = tid & 63;
  const int wv = __builtin_amdgcn_readfirstlane(tid >> 6);  // force SGPR
  const int kbase = wv * 64;
  const int grow = (lane >> 4) * 512 + d0 + (lane & 15);    // gate row in [0,2048)

  // persistent W slice: 64 floats/thread in VGPRs
  float wreg[64];
  #pragma unroll
  for (int kq = 0; kq < 16; kq++)
    *(float4*)&wreg[kq * 4] =
        *(const float4*)(W + (size_t)grow * HDIM + kbase + kq * 4);

  float wx[10];
  if (!IS_DEC) {
    #pragma unroll
    for (int i = 0; i < 10; i++)
      wx[i] = Wih[(size_t)grow * DDIM + wv * 10 + i];
  }

  if (tid < 64) sbias[tid] = bias[(tid >> 4) * 512 + d0 + (tid & 15)];
  if (IS_DEC && jt < 20) {
    for (int i = tid; i < 2048; i += 512)
      fcw_lds[i >> 9][i & 511] = fcW[(size_t)(jt * 4 + (i >> 9)) * HDIM + (i & 511)];
  }

  const int eb = tid >> 4, ed = tid & 15;  // elementwise (row, dim) ownership
  float c_reg = IS_DEC ? c_init[(size_t)(r0 + eb) * HDIM + d0 + ed] : 0.f;
  __syncthreads();

  const int t_begin = IS_DEC ? 1 : 0;
  for (int t = t_begin; t < TT; t++) {
    const float* hin = (t & 1) ? hB : hA;
    float* hout = (t & 1) ? hA : hB;

    // ---- decoder: y partial for recon slot t-1 = fc(h_t = hin) ----
    if (IS_DEC && jt < 20) {
      const int yr = tid >> 4, yf = tid & 15;
      const float4* hv = (const float4*)(hin + (size_t)(r0 + yr) * HDIM);
      float ya0 = 0.f, ya1 = 0.f, ya2 = 0.f, ya3 = 0.f;
      #pragma unroll
      for (int jj = 0; jj < 8; jj++) {
        const int kq = yf + jj * 16;
        float4 h4 = hv[kq];
        float4 w0 = *(const float4*)&fcw_lds[0][kq * 4];
        float4 w1 = *(const float4*)&fcw_lds[1][kq * 4];
        float4 w2 = *(const float4*)&fcw_lds[2][kq * 4];
        float4 w3 = *(const float4*)&fcw_lds[3][kq * 4];
        ya0 += h4.x * w0.x + h4.y * w0.y + h4.z * w0.z + h4.w * w0.w;
        ya1 += h4.x * w1.x + h4.y * w1.y + h4.z * w1.z + h4.w * w1.w;
        ya2 += h4.x * w2.x + h4.y * w2.y + h4.z * w2.z + h4.w * w2.w;
        ya3 += h4.x * w3.x + h4.y * w3.y + h4.z * w3.z + h4.w * w3.w;
      }
      *(float4*)&ypart[yr * 68 + yf * 4] = make_float4(ya0, ya1, ya2, ya3);
    }

    // ---- gates: wave-uniform h (scalar loads) x register W ----
    #pragma unroll 2
    for (int b = 0; b < 32; b++) {
      const float* hb = hin + (size_t)(r0 + b) * HDIM + kbase;  // uniform addr
      float a0 = 0.f, a1 = 0.f, a2 = 0.f, a3 = 0.f;
      #pragma unroll
      for (int kk = 0; kk < 64; kk += 4) {
        a0 = fmaf(hb[kk + 0], wreg[kk + 0], a0);
        a1 = fmaf(hb[kk + 1], wreg[kk + 1], a1);
        a2 = fmaf(hb[kk + 2], wreg[kk + 2], a2);
        a3 = fmaf(hb[kk + 3], wreg[kk + 3], a3);
      }
      if (!IS_DEC) {
        const float* xb = traj + (size_t)(r0 + b) * ROWSTRIDE + t * DDIM + wv * 10;
        #pragma unroll
        for (int i = 0; i < 10; i += 2) {
          a0 = fmaf(xb[i], wx[i], a0);
          a1 = fmaf(xb[i + 1], wx[i + 1], a1);
        }
      }
      partials[wv * 2052 + b * 64 + lane] = (a0 + a1) + (a2 + a3);
    }
    __syncthreads();

    // ---- reduce 8 wave-partials + bias (each thread: 4 gate values) ----
    {
      const int idx = tid << 2;
      float4 b4 = *(const float4*)&sbias[idx & 63];
      float4 p0 = *(const float4*)&partials[idx];
      float4 p1 = *(const float4*)&partials[2052 + idx];
      float4 p2 = *(const float4*)&partials[4104 + idx];
      float4 p3 = *(const float4*)&partials[6156 + idx];
      float4 p4 = *(const float4*)&partials[8208 + idx];
      float4 p5 = *(const float4*)&partials[10260 + idx];
      float4 p6 = *(const float4*)&partials[12312 + idx];
      float4 p7 = *(const float4*)&partials[14364 + idx];
      float4 rv;
      rv.x = ((b4.x + p0.x) + (p1.x + p2.x)) + ((p3.x + p4.x) + (p5.x + p6.x)) + p7.x;
      rv.y = ((b4.y + p0.y) + (p1.y + p2.y)) + ((p3.y + p4.y) + (p5.y + p6.y)) + p7.y;
      rv.z = ((b4.z + p0.z) + (p1.z + p2.z)) + ((p3.z + p4.z) + (p5.z + p6.z)) + p7.z;
      rv.w = ((b4.w + p0.w) + (p1.w + p2.w)) + ((p3.w + p4.w) + (p5.w + p6.w)) + p7.w;
      *(float4*)&reduced[idx] = rv;
    }
    if (IS_DEC && jt < 20 && tid < 128) {
      const int yr = tid >> 2, yd = tid & 3;
      float acc = fcb[jt * 4 + yd];
      #pragma unroll
      for (int f = 0; f < 16; f++) acc += ypart[yr * 68 + f * 4 + yd];
      recon[(size_t)(r0 + yr) * ROWSTRIDE + (size_t)(t - 1) * DDIM + jt * 4 + yd] = acc;
    }
    __syncthreads();

    // ---- fused elementwise; c stays in a VGPR ----
    {
      float ig = reduced[eb * 64 + ed];
      float fg = reduced[eb * 64 + 16 + ed];
      float gg = reduced[eb * 64 + 32 + ed];
      float og = reduced[eb * 64 + 48 + ed];
      float cn = sigmoidf_(fg) * c_reg + sigmoidf_(ig) * tanhf(gg);
      c_reg = cn;
      hout[(size_t)(r0 + eb) * HDIM + d0 + ed] = sigmoidf_(og) * tanhf(cn);
    }

    // ---- group barrier (skip on encoder's final step) ----
    if (IS_DEC || t < TT - 1) {
      __syncthreads();
      if (tid == 0) {
        __threadfence();
        __hip_atomic_fetch_add(cnt, 1, __ATOMIC_RELEASE, __HIP_MEMORY_SCOPE_AGENT);
        const int target = 32 * (t - t_begin + 1);
        while (__hip_atomic_load(cnt, __ATOMIC_ACQUIRE, __HIP_MEMORY_SCOPE_AGENT) < target)
          __builtin_amdgcn_s_sleep(1);
        __threadfence();
      }
      __syncthreads();
      __builtin_amdgcn_s_dcache_inv();  // scalar cache may hold stale h
    }
  }

  // ---- decoder: final recon slot 255 = fc(h_256 = hA) ----
  if (IS_DEC) {
    if (jt < 20) {
      const int yr = tid >> 4, yf = tid & 15;
      const float4* hv = (const float4*)(hA + (size_t)(r0 + yr) * HDIM);
      float ya0 = 0.f, ya1 = 0.f, ya2 = 0.f, ya3 = 0.f;
      #pragma unroll
      for (int jj = 0; jj < 8; jj++) {
        const int kq = yf + jj * 16;
        float4 h4 = hv[kq];
        float4 w0 = *(const float4*)&fcw_lds[0][kq * 4];
        float4 w1 = *(const float4*)&fcw_lds[1][kq * 4];
        float4 w2 = *(const float4*)&fcw_lds[2][kq * 4];
        float4 w3 = *(const float4*)&fcw_lds[3][kq * 4];
        ya0 += h4.x * w0.x + h4.y * w0.y + h4.z * w0.z + h4.w * w0.w;
        ya1 += h4.x * w1.x + h4.y * w1.y + h4.z * w1.z + h4.w * w1.w;
        ya2 += h4.x * w2.x + h4.y * w2.y + h4.z * w2.z + h4.w * w2.w;
        ya3 += h4.x * w3.x + h4.y * w3.y + h4.z * w3.z + h4.w * w3.w;
      }
      *(float4*)&ypart[yr * 68 + yf * 4] = make_float4(ya0, ya1, ya2, ya3);
    }
    __syncthreads();
    if (jt < 20 && tid < 128) {
      const int yr = tid >> 2, yd = tid & 3;
      float acc = fcb[jt * 4 + yd];
      #pragma unroll
      for (int f = 0; f < 16; f++) acc += ypart[yr * 68 + f * 4 + yd];
      recon[(size_t)(r0 + yr) * ROWSTRIDE + (size_t)255 * DDIM + jt * 4 + yd] = acc;
    }
  }
}

// ---------------- vector quantizer ----------------------------------------------
__global__ __launch_bounds__(256) void vq_kernel(
    const float* __restrict__ z, const float* __restrict__ emb,
    float* __restrict__ quant, float* __restrict__ vq_part,
    float* __restrict__ out_idx) {
  __shared__ float sz[512];
  __shared__ float sd[256];
  __shared__ int si[256];
  int b = blockIdx.x, tid = threadIdx.x;
  sz[tid] = z[(size_t)b * HDIM + tid];
  sz[tid + 256] = z[(size_t)b * HDIM + 256 + tid];
  __syncthreads();
  float bd = 3.4e38f;
  int bk = 0;
  for (int k = tid; k < 512; k += 256) {
    const float4* e4 = (const float4*)(emb + (size_t)k * HDIM);
    const float4* z4 = (const float4*)sz;
    float dot = 0.f, ee = 0.f;
    #pragma unroll 4
    for (int q = 0; q < 128; q++) {
      float4 ev = e4[q], zv = z4[q];
      dot += ev.x * zv.x + ev.y * zv.y + ev.z * zv.z + ev.w * zv.w;
      ee += ev.x * ev.x + ev.y * ev.y + ev.z * ev.z + ev.w * ev.w;
    }
    float dist = ee - 2.f * dot;
    if (dist < bd) { bd = dist; bk = k; }
  }
  sd[tid] = bd; si[tid] = bk;
  __syncthreads();
  for (int s = 128; s > 0; s >>= 1) {
    if (tid < s) {
      float od = sd[tid + s]; int ok = si[tid + s];
      if (od < sd[tid] || (od == sd[tid] && ok < si[tid])) { sd[tid] = od; si[tid] = ok; }
    }
    __syncthreads();
  }
  int kbest = si[0];
  __syncthreads();
  float e0 = emb[(size_t)kbest * HDIM + tid];
  float e1 = emb[(size_t)kbest * HDIM + 256 + tid];
  quant[(size_t)b * HDIM + tid] = e0;
  quant[(size_t)b * HDIM + 256 + tid] = e1;
  float q0 = e0 - sz[tid], q1 = e1 - sz[tid + 256];
  sd[tid] = q0 * q0 + q1 * q1;
  __syncthreads();
  for (int st = 128; st > 0; st >>= 1) {
    if (tid < st) sd[tid] += sd[tid + st];
    __syncthreads();
  }
  if (tid == 0) { vq_part[b] = sd[0]; out_idx[b] = (float)kbest; }
}

__global__ __launch_bounds__(256) void vq_reduce_kernel(const float* __restrict__ vq_part,
                                                        float* __restrict__ out_loss) {
  __shared__ float s[256];
  int tid = threadIdx.x;
  s[tid] = vq_part[tid];
  __syncthreads();
  for (int st = 128; st > 0; st >>= 1) {
    if (tid < st) s[tid] += s[tid + st];
    __syncthreads();
  }
  if (tid == 0) out_loss[0] = s[0] * 1.25f / (float)(BB * HDIM);
}

extern "C" void kernel_launch(void* const* d_in, const int* in_sizes, int n_in,
                              void* d_out, int out_size, void* d_ws, size_t ws_size,
                              hipStream_t stream) {
  const float* traj = (const float*)d_in[0];
  const float* eWih = (const float*)d_in[2];
  const float* eWhh = (const float*)d_in[3];
  const float* eb1  = (const float*)d_in[4];
  const float* eb2  = (const float*)d_in[5];
  const float* emb  = (const float*)d_in[6];
  const float* dWih = (const float*)d_in[7];
  const float* dWhh = (const float*)d_in[8];
  const float* db1  = (const float*)d_in[9];
  const float* db2  = (const float*)d_in[10];
  const float* fcW  = (const float*)d_in[11];
  const float* fcb  = (const float*)d_in[12];

  float* out = (float*)d_out;
  float* recon = out;
  float* out_loss = out + 5242880;
  float* out_idx = out + 5242881;

  float* ws = (float*)d_ws;
  float* hA      = ws + WS_HA;
  float* cD      = ws + WS_CD;
  int*   bar     = (int*)(ws + WS_BAR);
  float* hB      = ws + WS_HB;
  float* quant   = ws + WS_QUANT;
  float* vq_part = ws + WS_VQP;
  float* b_enc   = ws + WS_BENC;
  float* b_dec0  = ws + WS_BDEC0;
  float* b_eff   = ws + WS_BEFF;
  float* W_eff   = ws + WS_WEFF;

  // zero hA, cD, barrier counters (263168 floats = 65792 float4)
  zero_kernel<<<257, 256, 0, stream>>>((float4*)ws, 65792);
  bias_init_kernel<<<8, 256, 0, stream>>>(eb1, eb2, db1, db2, dWih, fcb,
                                          b_enc, b_dec0, b_eff);
  fold_kernel<<<2048, 256, 0, stream>>>(dWih, dWhh, fcW, W_eff);

  // encoder: t=0..255 persistent (h0 = zeros in hA); z lands in hA
  lstm_persist<0><<<256, 512, 0, stream>>>(
      eWhh, eWih, b_enc, traj, nullptr, nullptr, nullptr, nullptr, hA, hB, bar);

  vq_kernel<<<256, 256, 0, stream>>>(hA, emb, quant, vq_part, out_idx);
  vq_reduce_kernel<<<1, 256, 0, stream>>>(vq_part, out_loss);

  // decoder t=0 (plain dWhh, x=0): h_1 -> hB, c_1 -> cD
  lstm_step_kernel<<<512, 256, 0, stream>>>(nullptr, nullptr, dWhh, b_dec0,
                                            quant, cD, hB);
  // decoder t=1..255 persistent with W_eff; recon fused
  lstm_persist<1><<<256, 512, 0, stream>>>(
      W_eff, nullptr, b_eff, nullptr, cD, fcW, fcb, recon, hA, hB, bar + 512);
}

// Round 5
// 8661.898 us; speedup vs baseline: 5.0072x; 2.7466x over previous
//
#include <hip/hip_runtime.h>
#include <math.h>

// B=256, T=256, D=80, H=512, 4H=2048, K=512
#define BB 256
#define TT 256
#define DDIM 80
#define HDIM 512
#define ROWSTRIDE 20480   // T*D

// ws layout (float offsets)
#define WS_HA    0          // 131072 (zeroed: enc h0 / final z)
#define WS_CD    131072     // 131072 (zeroed: dec cell state)
#define WS_BAR   262144     // 1024 ints (zeroed)
#define WS_HB    263168     // 131072
#define WS_QUANT 394240     // 131072
#define WS_VQP   525312     // 256
#define WS_BENC  525568     // 2048
#define WS_BDEC0 527616     // 2048
#define WS_BEFF  529664     // 2048
#define WS_WEFF  531712     // 1048576

__device__ __forceinline__ float sigmoidf_(float v) { return 1.0f / (1.0f + expf(-v)); }

// LLC-coherent (bypass L1/L2) primitives — no cache fences needed for h exchange.
__device__ __forceinline__ void llc_store_f32(float* p, float v) {
  asm volatile("global_store_dword %0, %1, off sc0 sc1" :: "v"(p), "v"(v) : "memory");
}
__device__ __forceinline__ int llc_load_i32(const int* p) {
  int v;
  asm volatile("global_load_dword %0, %1, off sc0 sc1\n\ts_waitcnt vmcnt(0)"
               : "=v"(v) : "v"(p) : "memory");
  return v;
}
__device__ __forceinline__ float4 llc_load_f4(const float4* p) {
  float4 v;
  asm volatile("global_load_dwordx4 %0, %1, off sc0 sc1"
               : "=v"(v) : "v"(p) : "memory");
  return v;
}
__device__ __forceinline__ void wait_vm0() {
  asm volatile("s_waitcnt vmcnt(0)" ::: "memory");
}

__global__ __launch_bounds__(256) void zero_kernel(float4* __restrict__ p, int n4) {
  int i = blockIdx.x * 256 + threadIdx.x;
  if (i < n4) p[i] = make_float4(0.f, 0.f, 0.f, 0.f);
}

__global__ __launch_bounds__(256) void bias_init_kernel(
    const float* __restrict__ eb1, const float* __restrict__ eb2,
    const float* __restrict__ db1, const float* __restrict__ db2,
    const float* __restrict__ dWih, const float* __restrict__ fcb,
    float* __restrict__ b_enc, float* __restrict__ b_dec0,
    float* __restrict__ b_eff) {
  int n = blockIdx.x * 256 + threadIdx.x;
  b_enc[n] = eb1[n] + eb2[n];
  float bd = db1[n] + db2[n];
  b_dec0[n] = bd;
  float acc = bd;
  #pragma unroll 16
  for (int d = 0; d < DDIM; d++) acc += dWih[n * DDIM + d] * fcb[d];
  b_eff[n] = acc;
}

// W_eff = dec_W_hh + dec_W_ih @ fc_W  (2048x512, K=80)
__global__ __launch_bounds__(256) void fold_kernel(
    const float* __restrict__ dWih, const float* __restrict__ dWhh,
    const float* __restrict__ fcW, float* __restrict__ W_eff) {
  int n = blockIdx.x;
  int tid = threadIdx.x;
  __shared__ float sw[DDIM];
  if (tid < DDIM) sw[tid] = dWih[n * DDIM + tid];
  __syncthreads();
  for (int k = tid; k < HDIM; k += 256) {
    float acc = dWhh[n * HDIM + k];
    #pragma unroll 16
    for (int d = 0; d < DDIM; d++) acc += sw[d] * fcW[d * HDIM + k];
    W_eff[n * HDIM + k] = acc;
  }
}

// ---------------- single LSTM step (decoder t=0 only; x = 0) ---------------------
__global__ __launch_bounds__(256) void lstm_step_kernel(
    const float* __restrict__ Whh, const float* __restrict__ bias,
    const float* __restrict__ h_in, float* __restrict__ c,
    float* __restrict__ h_out) {
  __shared__ float sh[16][516];
  int tid = threadIdx.x;
  int rt = blockIdx.x & 15, jt = blockIdx.x >> 4;
  int row0 = rt << 4;
  for (int i = tid; i < 2048; i += 256) {
    int r = i >> 7, kq = i & 127;
    float4 v = *(const float4*)(h_in + (size_t)(row0 + r) * HDIM + (kq << 2));
    *(float4*)&sh[r][kq << 2] = v;
  }
  __syncthreads();
  int r = tid & 15, j0 = tid >> 4;
  int j = (jt << 4) + j0;
  float a0 = bias[j], a1 = bias[512 + j], a2 = bias[1024 + j], a3 = bias[1536 + j];
  const float4* w0 = (const float4*)(Whh + (size_t)j * HDIM);
  const float4* w1 = (const float4*)(Whh + (size_t)(512 + j) * HDIM);
  const float4* w2 = (const float4*)(Whh + (size_t)(1024 + j) * HDIM);
  const float4* w3 = (const float4*)(Whh + (size_t)(1536 + j) * HDIM);
  const float4* hv = (const float4*)&sh[r][0];
  #pragma unroll 4
  for (int kq = 0; kq < 128; kq++) {
    float4 h4 = hv[kq];
    float4 q0 = w0[kq], q1 = w1[kq], q2 = w2[kq], q3 = w3[kq];
    a0 += h4.x * q0.x + h4.y * q0.y + h4.z * q0.z + h4.w * q0.w;
    a1 += h4.x * q1.x + h4.y * q1.y + h4.z * q1.z + h4.w * q1.w;
    a2 += h4.x * q2.x + h4.y * q2.y + h4.z * q2.z + h4.w * q2.w;
    a3 += h4.x * q3.x + h4.y * q3.y + h4.z * q3.z + h4.w * q3.w;
  }
  size_t idx = (size_t)(row0 + r) * HDIM + j;
  float cv = c[idx];
  float cn = sigmoidf_(a1) * cv + sigmoidf_(a0) * tanhf(a2);
  float hn = sigmoidf_(a3) * tanhf(cn);
  c[idx] = cn;
  h_out[idx] = hn;
}

// ---------------- persistent register-stationary LSTM ----------------------------
// 256 blocks (1/CU), 512 threads. Block (rt=bid&7, jt=bid>>3): rows [rt*32,+32),
// h-dims [jt*16,+16) -> 64 gate rows. Wave wv owns K-chunk [wv*64,+64); lane =
// gate row; W slice in 64 VGPRs for all 256 steps. Per step: h tile staged
// coalesced from LLC (sc0 sc1) into LDS; gates read broadcast ds_read_b128.
// h exchange entirely via LLC -> barrier needs NO cache maintenance.
template <int IS_DEC>
__global__ __launch_bounds__(512, 2) void lstm_persist(
    const float* __restrict__ W,      // enc: eWhh; dec: W_eff  [2048][512]
    const float* __restrict__ Wih,    // enc only [2048][80]
    const float* __restrict__ bias,   // enc: b_enc; dec: b_eff [2048]
    const float* __restrict__ traj,   // enc only
    const float* __restrict__ c_init, // dec: cD (holds c_1)
    const float* __restrict__ fcW, const float* __restrict__ fcb,
    float* __restrict__ recon,
    float* __restrict__ hA, float* __restrict__ hB,
    int* __restrict__ bar) {
  // smem layout (floats): h_lds[32][516] @0 | partials[8][2052] @16512 |
  // reduced[2048] @32928 | sbias[64] @34976 | enc x_lds[32][84] / dec fcw[4][512]
  // @35040 | dec ypart[32][68] @37088
  __shared__ float smem[IS_DEC ? 39264 : 37728];
  float* h_lds = smem;
  float* partials = smem + 16512;
  float* reduced = smem + 32928;
  float* sbias = smem + 34976;
  float* x_lds = smem + 35040;       // enc
  float* fcw = smem + 35040;         // dec
  float* ypart = smem + 37088;       // dec

  const int tid = threadIdx.x;
  const int bid = blockIdx.x;
  const int rt = bid & 7, jt = bid >> 3;
  const int r0 = rt * 32, d0 = jt * 16;
  int* cnt = bar + rt * 64;

  const int lane = tid & 63;
  const int wv = __builtin_amdgcn_readfirstlane(tid >> 6);
  const int kbase = wv * 64;
  const int grow = (lane >> 4) * 512 + d0 + (lane & 15);  // gate row

  // persistent W slice: 64 floats/thread in VGPRs
  float wreg[64];
  #pragma unroll
  for (int kq = 0; kq < 16; kq++)
    *(float4*)&wreg[kq * 4] =
        *(const float4*)(W + (size_t)grow * HDIM + kbase + kq * 4);
  float wx[10];
  if (!IS_DEC) {
    #pragma unroll
    for (int i = 0; i < 10; i++)
      wx[i] = Wih[(size_t)grow * DDIM + wv * 10 + i];
  }
  if (tid < 64) sbias[tid] = bias[(tid >> 4) * 512 + d0 + (tid & 15)];
  if (IS_DEC && jt < 20) {
    for (int i = tid; i < 2048; i += 512)
      fcw[i] = fcW[(size_t)(jt * 4 + (i >> 9)) * HDIM + (i & 511)];
  }
  const int eb = tid >> 4, ed = tid & 15;
  float c_reg = IS_DEC ? c_init[(size_t)(r0 + eb) * HDIM + d0 + ed] : 0.f;
  __syncthreads();

  const int t_begin = IS_DEC ? 1 : 0;
  for (int t = t_begin; t < TT; t++) {
    const float* hin = (t & 1) ? hB : hA;
    float* hout = (t & 1) ? hA : hB;
    if (IS_DEC == 0 && t == 0) hin = hA;  // zeros

    // ---- stage h tile (32x512) from LLC into LDS, coalesced ----
    {
      const float4* gp = (const float4*)(hin + (size_t)r0 * HDIM);
      float4 t0 = llc_load_f4(gp + tid + 0 * 512);
      float4 t1 = llc_load_f4(gp + tid + 1 * 512);
      float4 t2 = llc_load_f4(gp + tid + 2 * 512);
      float4 t3 = llc_load_f4(gp + tid + 3 * 512);
      float4 t4 = llc_load_f4(gp + tid + 4 * 512);
      float4 t5 = llc_load_f4(gp + tid + 5 * 512);
      float4 t6 = llc_load_f4(gp + tid + 6 * 512);
      float4 t7 = llc_load_f4(gp + tid + 7 * 512);
      wait_vm0();
      #define SST(n, it) { int i = tid + (it)*512; \
        *(float4*)&h_lds[(i >> 7) * 516 + (i & 127) * 4] = t##n; }
      SST(0, 0); SST(1, 1); SST(2, 2); SST(3, 3);
      SST(4, 4); SST(5, 5); SST(6, 6); SST(7, 7);
      #undef SST
    }
    if (!IS_DEC) {  // stage x tile (32x80), cached (traj is read-only)
      for (int i = tid; i < 640; i += 512) {
        int row = i / 20, c4 = i % 20;
        float4 v = *(const float4*)(traj + (size_t)(r0 + row) * ROWSTRIDE +
                                    (size_t)t * DDIM + c4 * 4);
        *(float4*)&x_lds[row * 84 + c4 * 4] = v;
      }
    }
    __syncthreads();

    // ---- decoder: y partials for recon slot t-1 = fc(h_t = hin) ----
    if (IS_DEC && jt < 20) {
      const int yr = tid >> 4, yf = tid & 15;
      float ya0 = 0.f, ya1 = 0.f, ya2 = 0.f, ya3 = 0.f;
      #pragma unroll
      for (int jj = 0; jj < 8; jj++) {
        const int kq = yf + jj * 16;
        float4 h4 = *(const float4*)&h_lds[yr * 516 + kq * 4];
        float4 w0 = *(const float4*)&fcw[0 * 512 + kq * 4];
        float4 w1 = *(const float4*)&fcw[1 * 512 + kq * 4];
        float4 w2 = *(const float4*)&fcw[2 * 512 + kq * 4];
        float4 w3 = *(const float4*)&fcw[3 * 512 + kq * 4];
        ya0 += h4.x * w0.x + h4.y * w0.y + h4.z * w0.z + h4.w * w0.w;
        ya1 += h4.x * w1.x + h4.y * w1.y + h4.z * w1.z + h4.w * w1.w;
        ya2 += h4.x * w2.x + h4.y * w2.y + h4.z * w2.z + h4.w * w2.w;
        ya3 += h4.x * w3.x + h4.y * w3.y + h4.z * w3.z + h4.w * w3.w;
      }
      *(float4*)&ypart[yr * 68 + yf * 4] = make_float4(ya0, ya1, ya2, ya3);
    }

    // ---- gates: LDS-broadcast h x register W ----
    #pragma unroll 2
    for (int b = 0; b < 32; b++) {
      const float* hb = &h_lds[b * 516 + kbase];
      float a0 = 0.f, a1 = 0.f, a2 = 0.f, a3 = 0.f;
      #pragma unroll
      for (int k4 = 0; k4 < 16; k4++) {
        float4 h4 = *(const float4*)&hb[k4 * 4];
        a0 = fmaf(h4.x, wreg[k4 * 4 + 0], a0);
        a1 = fmaf(h4.y, wreg[k4 * 4 + 1], a1);
        a2 = fmaf(h4.z, wreg[k4 * 4 + 2], a2);
        a3 = fmaf(h4.w, wreg[k4 * 4 + 3], a3);
      }
      if (!IS_DEC) {
        const float2* xp = (const float2*)&x_lds[b * 84 + wv * 10];
        #pragma unroll
        for (int i = 0; i < 5; i++) {
          float2 xv = xp[i];
          a0 = fmaf(xv.x, wx[2 * i], a0);
          a1 = fmaf(xv.y, wx[2 * i + 1], a1);
        }
      }
      partials[wv * 2052 + b * 64 + lane] = (a0 + a1) + (a2 + a3);
    }
    __syncthreads();

    // ---- reduce 8 wave-partials + bias ----
    {
      const int idx = tid << 2;
      float4 b4 = *(const float4*)&sbias[idx & 63];
      float4 p0 = *(const float4*)&partials[idx];
      float4 p1 = *(const float4*)&partials[2052 + idx];
      float4 p2 = *(const float4*)&partials[4104 + idx];
      float4 p3 = *(const float4*)&partials[6156 + idx];
      float4 p4 = *(const float4*)&partials[8208 + idx];
      float4 p5 = *(const float4*)&partials[10260 + idx];
      float4 p6 = *(const float4*)&partials[12312 + idx];
      float4 p7 = *(const float4*)&partials[14364 + idx];
      float4 rv;
      rv.x = ((b4.x + p0.x) + (p1.x + p2.x)) + ((p3.x + p4.x) + (p5.x + p6.x)) + p7.x;
      rv.y = ((b4.y + p0.y) + (p1.y + p2.y)) + ((p3.y + p4.y) + (p5.y + p6.y)) + p7.y;
      rv.z = ((b4.z + p0.z) + (p1.z + p2.z)) + ((p3.z + p4.z) + (p5.z + p6.z)) + p7.z;
      rv.w = ((b4.w + p0.w) + (p1.w + p2.w)) + ((p3.w + p4.w) + (p5.w + p6.w)) + p7.w;
      *(float4*)&reduced[idx] = rv;
    }
    if (IS_DEC && jt < 20 && tid < 128) {
      const int yr = tid >> 2, yd = tid & 3;
      float acc = fcb[jt * 4 + yd];
      #pragma unroll
      for (int f = 0; f < 16; f++) acc += ypart[yr * 68 + f * 4 + yd];
      recon[(size_t)(r0 + yr) * ROWSTRIDE + (size_t)(t - 1) * DDIM + jt * 4 + yd] = acc;
    }
    __syncthreads();

    // ---- fused elementwise; c in VGPR; h store -> LLC ----
    {
      float ig = reduced[eb * 64 + ed];
      float fg = reduced[eb * 64 + 16 + ed];
      float gg = reduced[eb * 64 + 32 + ed];
      float og = reduced[eb * 64 + 48 + ed];
      float cn = sigmoidf_(fg) * c_reg + sigmoidf_(ig) * tanhf(gg);
      c_reg = cn;
      llc_store_f32(&hout[(size_t)(r0 + eb) * HDIM + d0 + ed],
                    sigmoidf_(og) * tanhf(cn));
      wait_vm0();  // per-thread: h store is in LLC before we can pass the barrier
    }

    // ---- group barrier: all threads drained; atomic signal; relaxed spin ----
    if (IS_DEC || t < TT - 1) {
      __syncthreads();
      if (tid == 0) {
        atomicAdd(cnt, 1);
        const int target = 32 * (t - t_begin + 1);
        while (llc_load_i32(cnt) < target) __builtin_amdgcn_s_sleep(2);
      }
      __syncthreads();
    }
  }

  // ---- decoder: final recon slot 255 = fc(h_256 = hA) ----
  if (IS_DEC) {
    {
      const float4* gp = (const float4*)(hA + (size_t)r0 * HDIM);
      float4 t0 = llc_load_f4(gp + tid + 0 * 512);
      float4 t1 = llc_load_f4(gp + tid + 1 * 512);
      float4 t2 = llc_load_f4(gp + tid + 2 * 512);
      float4 t3 = llc_load_f4(gp + tid + 3 * 512);
      float4 t4 = llc_load_f4(gp + tid + 4 * 512);
      float4 t5 = llc_load_f4(gp + tid + 5 * 512);
      float4 t6 = llc_load_f4(gp + tid + 6 * 512);
      float4 t7 = llc_load_f4(gp + tid + 7 * 512);
      wait_vm0();
      #define SST(n, it) { int i = tid + (it)*512; \
        *(float4*)&h_lds[(i >> 7) * 516 + (i & 127) * 4] = t##n; }
      SST(0, 0); SST(1, 1); SST(2, 2); SST(3, 3);
      SST(4, 4); SST(5, 5); SST(6, 6); SST(7, 7);
      #undef SST
    }
    __syncthreads();
    if (jt < 20) {
      const int yr = tid >> 4, yf = tid & 15;
      float ya0 = 0.f, ya1 = 0.f, ya2 = 0.f, ya3 = 0.f;
      #pragma unroll
      for (int jj = 0; jj < 8; jj++) {
        const int kq = yf + jj * 16;
        float4 h4 = *(const float4*)&h_lds[yr * 516 + kq * 4];
        float4 w0 = *(const float4*)&fcw[0 * 512 + kq * 4];
        float4 w1 = *(const float4*)&fcw[1 * 512 + kq * 4];
        float4 w2 = *(const float4*)&fcw[2 * 512 + kq * 4];
        float4 w3 = *(const float4*)&fcw[3 * 512 + kq * 4];
        ya0 += h4.x * w0.x + h4.y * w0.y + h4.z * w0.z + h4.w * w0.w;
        ya1 += h4.x * w1.x + h4.y * w1.y + h4.z * w1.z + h4.w * w1.w;
        ya2 += h4.x * w2.x + h4.y * w2.y + h4.z * w2.z + h4.w * w2.w;
        ya3 += h4.x * w3.x + h4.y * w3.y + h4.z * w3.z + h4.w * w3.w;
      }
      *(float4*)&ypart[yr * 68 + yf * 4] = make_float4(ya0, ya1, ya2, ya3);
    }
    __syncthreads();
    if (jt < 20 && tid < 128) {
      const int yr = tid >> 2, yd = tid & 3;
      float acc = fcb[jt * 4 + yd];
      #pragma unroll
      for (int f = 0; f < 16; f++) acc += ypart[yr * 68 + f * 4 + yd];
      recon[(size_t)(r0 + yr) * ROWSTRIDE + (size_t)255 * DDIM + jt * 4 + yd] = acc;
    }
  }
}

// ---------------- vector quantizer ----------------------------------------------
__global__ __launch_bounds__(256) void vq_kernel(
    const float* __restrict__ z, const float* __restrict__ emb,
    float* __restrict__ quant, float* __restrict__ vq_part,
    float* __restrict__ out_idx) {
  __shared__ float sz[512];
  __shared__ float sd[256];
  __shared__ int si[256];
  int b = blockIdx.x, tid = threadIdx.x;
  sz[tid] = z[(size_t)b * HDIM + tid];
  sz[tid + 256] = z[(size_t)b * HDIM + 256 + tid];
  __syncthreads();
  float bd = 3.4e38f;
  int bk = 0;
  for (int k = tid; k < 512; k += 256) {
    const float4* e4 = (const float4*)(emb + (size_t)k * HDIM);
    const float4* z4 = (const float4*)sz;
    float dot = 0.f, ee = 0.f;
    #pragma unroll 4
    for (int q = 0; q < 128; q++) {
      float4 ev = e4[q], zv = z4[q];
      dot += ev.x * zv.x + ev.y * zv.y + ev.z * zv.z + ev.w * zv.w;
      ee += ev.x * ev.x + ev.y * ev.y + ev.z * ev.z + ev.w * ev.w;
    }
    float dist = ee - 2.f * dot;
    if (dist < bd) { bd = dist; bk = k; }
  }
  sd[tid] = bd; si[tid] = bk;
  __syncthreads();
  for (int s = 128; s > 0; s >>= 1) {
    if (tid < s) {
      float od = sd[tid + s]; int ok = si[tid + s];
      if (od < sd[tid] || (od == sd[tid] && ok < si[tid])) { sd[tid] = od; si[tid] = ok; }
    }
    __syncthreads();
  }
  int kbest = si[0];
  __syncthreads();
  float e0 = emb[(size_t)kbest * HDIM + tid];
  float e1 = emb[(size_t)kbest * HDIM + 256 + tid];
  quant[(size_t)b * HDIM + tid] = e0;
  quant[(size_t)b * HDIM + 256 + tid] = e1;
  float q0 = e0 - sz[tid], q1 = e1 - sz[tid + 256];
  sd[tid] = q0 * q0 + q1 * q1;
  __syncthreads();
  for (int st = 128; st > 0; st >>= 1) {
    if (tid < st) sd[tid] += sd[tid + st];
    __syncthreads();
  }
  if (tid == 0) { vq_part[b] = sd[0]; out_idx[b] = (float)kbest; }
}

__global__ __launch_bounds__(256) void vq_reduce_kernel(const float* __restrict__ vq_part,
                                                        float* __restrict__ out_loss) {
  __shared__ float s[256];
  int tid = threadIdx.x;
  s[tid] = vq_part[tid];
  __syncthreads();
  for (int st = 128; st > 0; st >>= 1) {
    if (tid < st) s[tid] += s[tid + st];
    __syncthreads();
  }
  if (tid == 0) out_loss[0] = s[0] * 1.25f / (float)(BB * HDIM);
}

extern "C" void kernel_launch(void* const* d_in, const int* in_sizes, int n_in,
                              void* d_out, int out_size, void* d_ws, size_t ws_size,
                              hipStream_t stream) {
  const float* traj = (const float*)d_in[0];
  const float* eWih = (const float*)d_in[2];
  const float* eWhh = (const float*)d_in[3];
  const float* eb1  = (const float*)d_in[4];
  const float* eb2  = (const float*)d_in[5];
  const float* emb  = (const float*)d_in[6];
  const float* dWih = (const float*)d_in[7];
  const float* dWhh = (const float*)d_in[8];
  const float* db1  = (const float*)d_in[9];
  const float* db2  = (const float*)d_in[10];
  const float* fcW  = (const float*)d_in[11];
  const float* fcb  = (const float*)d_in[12];

  float* out = (float*)d_out;
  float* recon = out;
  float* out_loss = out + 5242880;
  float* out_idx = out + 5242881;

  float* ws = (float*)d_ws;
  float* hA      = ws + WS_HA;
  float* cD      = ws + WS_CD;
  int*   bar     = (int*)(ws + WS_BAR);
  float* hB      = ws + WS_HB;
  float* quant   = ws + WS_QUANT;
  float* vq_part = ws + WS_VQP;
  float* b_enc   = ws + WS_BENC;
  float* b_dec0  = ws + WS_BDEC0;
  float* b_eff   = ws + WS_BEFF;
  float* W_eff   = ws + WS_WEFF;

  // zero hA, cD, barrier counters
  zero_kernel<<<257, 256, 0, stream>>>((float4*)ws, 65792);
  bias_init_kernel<<<8, 256, 0, stream>>>(eb1, eb2, db1, db2, dWih, fcb,
                                          b_enc, b_dec0, b_eff);
  fold_kernel<<<2048, 256, 0, stream>>>(dWih, dWhh, fcW, W_eff);

  // encoder: t=0..255 persistent (h0 = zeros in hA); z lands in hA
  lstm_persist<0><<<256, 512, 0, stream>>>(
      eWhh, eWih, b_enc, traj, nullptr, nullptr, nullptr, nullptr, hA, hB, bar);

  vq_kernel<<<256, 256, 0, stream>>>(hA, emb, quant, vq_part, out_idx);
  vq_reduce_kernel<<<1, 256, 0, stream>>>(vq_part, out_loss);

  // decoder t=0 (plain dWhh, x=0): h_1 -> hB, c_1 -> cD
  lstm_step_kernel<<<512, 256, 0, stream>>>(dWhh, b_dec0, quant, cD, hB);
  // decoder t=1..255 persistent with W_eff; recon fused
  lstm_persist<1><<<256, 512, 0, stream>>>(
      W_eff, nullptr, b_eff, nullptr, cD, fcW, fcb, recon, hA, hB, bar + 512);
}

// Round 7
// 2683.734 us; speedup vs baseline: 16.1611x; 3.2276x over previous
//
#include <hip/hip_runtime.h>
#include <math.h>

// B=256, T=256, D=80, H=512, 4H=2048, K=512
#define BB 256
#define TT 256
#define DDIM 80
#define HDIM 512
#define ROWSTRIDE 20480   // T*D

// ws layout (float offsets)
#define WS_HA    0          // 131072 (zeroed: enc h0 / final z)
#define WS_CD    131072     // 131072 (zeroed: dec cell state)
#define WS_BAR   262144     // int flags: enc [0..255], dec [256..511]
#define WS_HB    263168
#define WS_QUANT 394240
#define WS_VQP   525312
#define WS_BENC  525568
#define WS_BDEC0 527616
#define WS_BEFF  529664
#define WS_WEFF  531712     // 2048*512

typedef _Float16 f16;
typedef f16 half4_t __attribute__((ext_vector_type(4)));
typedef f16 half8_t __attribute__((ext_vector_type(8)));
typedef float float4_t __attribute__((ext_vector_type(4)));

__device__ __forceinline__ float sigmoidf_(float v) { return 1.0f / (1.0f + expf(-v)); }

// LLC-coherent (bypass L1/L2) primitives
__device__ __forceinline__ void llc_store_f32(float* p, float v) {
  asm volatile("global_store_dword %0, %1, off sc0 sc1" :: "v"(p), "v"(v) : "memory");
}
__device__ __forceinline__ void llc_store_i32(int* p, int v) {
  asm volatile("global_store_dword %0, %1, off sc0 sc1" :: "v"(p), "v"(v) : "memory");
}
__device__ __forceinline__ int llc_load_i32(const int* p) {
  int v;
  asm volatile("global_load_dword %0, %1, off sc0 sc1\n\ts_waitcnt vmcnt(0)"
               : "=v"(v) : "v"(p) : "memory");
  return v;
}
__device__ __forceinline__ void wait_vm0() {
  asm volatile("s_waitcnt vmcnt(0)" ::: "memory");
}
// 8 LLC loads + waitcnt fused in ONE asm block: outputs are written by the
// block itself, so no consumer (incl. VALU cvt) can run before the wait.
// "=&v" early-clobber: outputs never alias the in-flight address registers.
__device__ __forceinline__ void llc_load_8xf4(
    const float4* p0, const float4* p1, const float4* p2, const float4* p3,
    const float4* p4, const float4* p5, const float4* p6, const float4* p7,
    float4& a0, float4& a1, float4& a2, float4& a3,
    float4& a4, float4& a5, float4& a6, float4& a7) {
  asm volatile(
      "global_load_dwordx4 %0, %8, off sc0 sc1\n\t"
      "global_load_dwordx4 %1, %9, off sc0 sc1\n\t"
      "global_load_dwordx4 %2, %10, off sc0 sc1\n\t"
      "global_load_dwordx4 %3, %11, off sc0 sc1\n\t"
      "global_load_dwordx4 %4, %12, off sc0 sc1\n\t"
      "global_load_dwordx4 %5, %13, off sc0 sc1\n\t"
      "global_load_dwordx4 %6, %14, off sc0 sc1\n\t"
      "global_load_dwordx4 %7, %15, off sc0 sc1\n\t"
      "s_waitcnt vmcnt(0)"
      : "=&v"(a0), "=&v"(a1), "=&v"(a2), "=&v"(a3),
        "=&v"(a4), "=&v"(a5), "=&v"(a6), "=&v"(a7)
      : "v"(p0), "v"(p1), "v"(p2), "v"(p3),
        "v"(p4), "v"(p5), "v"(p6), "v"(p7)
      : "memory");
}

__global__ __launch_bounds__(256) void zero_kernel(float4* __restrict__ p, int n4) {
  int i = blockIdx.x * 256 + threadIdx.x;
  if (i < n4) p[i] = make_float4(0.f, 0.f, 0.f, 0.f);
}

__global__ __launch_bounds__(256) void bias_init_kernel(
    const float* __restrict__ eb1, const float* __restrict__ eb2,
    const float* __restrict__ db1, const float* __restrict__ db2,
    const float* __restrict__ dWih, const float* __restrict__ fcb,
    float* __restrict__ b_enc, float* __restrict__ b_dec0,
    float* __restrict__ b_eff) {
  int n = blockIdx.x * 256 + threadIdx.x;
  b_enc[n] = eb1[n] + eb2[n];
  float bd = db1[n] + db2[n];
  b_dec0[n] = bd;
  float acc = bd;
  #pragma unroll 16
  for (int d = 0; d < DDIM; d++) acc += dWih[n * DDIM + d] * fcb[d];
  b_eff[n] = acc;
}

// W_eff = dec_W_hh + dec_W_ih @ fc_W  (2048x512, K=80)
__global__ __launch_bounds__(256) void fold_kernel(
    const float* __restrict__ dWih, const float* __restrict__ dWhh,
    const float* __restrict__ fcW, float* __restrict__ W_eff) {
  int n = blockIdx.x;
  int tid = threadIdx.x;
  __shared__ float sw[DDIM];
  if (tid < DDIM) sw[tid] = dWih[n * DDIM + tid];
  __syncthreads();
  for (int k = tid; k < HDIM; k += 256) {
    float acc = dWhh[n * HDIM + k];
    #pragma unroll 16
    for (int d = 0; d < DDIM; d++) acc += sw[d] * fcW[d * HDIM + k];
    W_eff[n * HDIM + k] = acc;
  }
}

// ---------------- single LSTM step (decoder t=0 only; x = 0) ---------------------
__global__ __launch_bounds__(256) void lstm_step_kernel(
    const float* __restrict__ Whh, const float* __restrict__ bias,
    const float* __restrict__ h_in, float* __restrict__ c,
    float* __restrict__ h_out) {
  __shared__ float sh[16][516];
  int tid = threadIdx.x;
  int rt = blockIdx.x & 15, jt = blockIdx.x >> 4;
  int row0 = rt << 4;
  for (int i = tid; i < 2048; i += 256) {
    int r = i >> 7, kq = i & 127;
    float4 v = *(const float4*)(h_in + (size_t)(row0 + r) * HDIM + (kq << 2));
    *(float4*)&sh[r][kq << 2] = v;
  }
  __syncthreads();
  int r = tid & 15, j0 = tid >> 4;
  int j = (jt << 4) + j0;
  float a0 = bias[j], a1 = bias[512 + j], a2 = bias[1024 + j], a3 = bias[1536 + j];
  const float4* w0 = (const float4*)(Whh + (size_t)j * HDIM);
  const float4* w1 = (const float4*)(Whh + (size_t)(512 + j) * HDIM);
  const float4* w2 = (const float4*)(Whh + (size_t)(1024 + j) * HDIM);
  const float4* w3 = (const float4*)(Whh + (size_t)(1536 + j) * HDIM);
  const float4* hv = (const float4*)&sh[r][0];
  #pragma unroll 4
  for (int kq = 0; kq < 128; kq++) {
    float4 h4 = hv[kq];
    float4 q0 = w0[kq], q1 = w1[kq], q2 = w2[kq], q3 = w3[kq];
    a0 += h4.x * q0.x + h4.y * q0.y + h4.z * q0.z + h4.w * q0.w;
    a1 += h4.x * q1.x + h4.y * q1.y + h4.z * q1.z + h4.w * q1.w;
    a2 += h4.x * q2.x + h4.y * q2.y + h4.z * q2.z + h4.w * q2.w;
    a3 += h4.x * q3.x + h4.y * q3.y + h4.z * q3.z + h4.w * q3.w;
  }
  size_t idx = (size_t)(row0 + r) * HDIM + j;
  float cv = c[idx];
  float cn = sigmoidf_(a1) * cv + sigmoidf_(a0) * tanhf(a2);
  float hn = sigmoidf_(a3) * tanhf(cn);
  c[idx] = cn;
  h_out[idx] = hn;
}

// ---------------- persistent MFMA LSTM (split-fp16, register-stationary W) -------
// 256 blocks (1/CU), 512 threads. Block (rt=bid&7, jt=bid>>3): rows [rt*32,+32),
// h-dims [jt*16,+16) -> 64 gate rows. Waves = (mt in 2) x (nt = gate type in 4).
// W slice split into fp16 hi/lo B-fragments in VGPRs (full K). Per step: h (+x)
// staged from LLC -> split-fp16 LDS; 4-term MFMA (exact split product) in fp32;
// elementwise with c in VGPR; h -> LLC; flag-array group barrier.
template <int IS_DEC>
__global__ __launch_bounds__(512, 2) void lstm_persist(
    const float* __restrict__ W,      // enc: eWhh; dec: W_eff  [2048][512]
    const float* __restrict__ Wih,    // enc only [2048][80]
    const float* __restrict__ bias,   // [2048]
    const float* __restrict__ traj,   // enc only
    const float* __restrict__ c_init, // dec: cD (holds c_1)
    const float* __restrict__ fcW, const float* __restrict__ fcb,
    float* __restrict__ recon,
    float* __restrict__ hA, float* __restrict__ hB,
    int* __restrict__ flags) {
  constexpr int KT  = IS_DEC ? 16 : 19;    // k-tiles of 32 (enc: 512 h + 80 x + pad)
  constexpr int AST = IS_DEC ? 520 : 616;  // f16 row stride (16B aligned)
  __shared__ f16 Ahi[32 * AST];
  __shared__ f16 Alo[32 * AST];
  __shared__ float red[32 * 68];           // gates, stride 68
  __shared__ float ypart[IS_DEC ? 8 * 516 : 4];

  const int tid = threadIdx.x;
  const int bid = blockIdx.x;
  const int rt = bid & 7, jt = bid >> 3;
  const int r0 = rt * 32, d0 = jt * 16;
  const int wv = __builtin_amdgcn_readfirstlane(tid >> 6);
  const int l15 = tid & 15;
  const int q = (tid >> 4) & 3;            // quad within wave
  const int mt = wv >> 2, nt = wv & 3;     // nt = gate type

  // splits v (f32x4) into hi/lo f16x4 and stores to Ahi/Alo at flat idx i
  #define SPLITW(vv, it) { \
    int i = tid + (it) * 512; \
    int off = (i >> 7) * AST + (i & 127) * 4; \
    half4_t hi4, lo4; \
    float f0 = vv.x, f1 = vv.y, f2 = vv.z, f3 = vv.w; \
    f16 a = (f16)f0, b = (f16)f1, cc = (f16)f2, d = (f16)f3; \
    hi4[0] = a; hi4[1] = b; hi4[2] = cc; hi4[3] = d; \
    lo4[0] = (f16)(f0 - (float)a); lo4[1] = (f16)(f1 - (float)b); \
    lo4[2] = (f16)(f2 - (float)cc); lo4[3] = (f16)(f3 - (float)d); \
    *(half4_t*)&Ahi[off] = hi4; *(half4_t*)&Alo[off] = lo4; }

  // ---- register-stationary W: split-fp16 B-fragments ----
  const int grow = nt * 512 + d0 + l15;    // global gate row
  half8_t Whi[KT], Wlo[KT];
  #pragma unroll
  for (int kt = 0; kt < KT; kt++) {
    #pragma unroll
    for (int j = 0; j < 8; j++) {
      int k = kt * 32 + q * 8 + j;
      float w;
      if (k < 512) w = W[(size_t)grow * HDIM + k];
      else {
        int kx = k - 512;
        w = (!IS_DEC && kx < DDIM) ? Wih[(size_t)grow * DDIM + kx] : 0.f;
      }
      f16 hi = (f16)w;
      Whi[kt][j] = hi;
      Wlo[kt][j] = (f16)(w - (float)hi);
    }
  }
  const float breg = bias[grow];

  // dec: fcW fragments for fused y (jt<5 covers 80 dims; k-split by wave)
  half8_t Fhi[2], Flo[2];
  float ybias = 0.f;
  if (IS_DEC && jt < 5) {
    const int drow = jt * 16 + l15;
    #pragma unroll
    for (int kk = 0; kk < 2; kk++) {
      const int kt = wv * 2 + kk;
      #pragma unroll
      for (int j = 0; j < 8; j++) {
        float w = fcW[(size_t)drow * HDIM + kt * 32 + q * 8 + j];
        f16 hi = (f16)w;
        Fhi[kk][j] = hi;
        Flo[kk][j] = (f16)(w - (float)hi);
      }
    }
    ybias = fcb[jt * 16 + (tid & 15)];
  }

  const int eb = tid >> 4, ed = tid & 15;  // elementwise (row, dim)
  float c_reg = IS_DEC ? c_init[(size_t)(r0 + eb) * HDIM + d0 + ed] : 0.f;
  __syncthreads();

  const int t_begin = IS_DEC ? 1 : 0;
  for (int t = t_begin; t < TT; t++) {
    const float* hin = (t & 1) ? hB : hA;
    float* hout = (t & 1) ? hA : hB;

    // ---- stage: h from LLC -> split-fp16 LDS (single fused load+wait asm) ----
    {
      const float4* gp = (const float4*)(hin + (size_t)r0 * HDIM);
      float4 v0, v1, v2, v3, v4, v5, v6, v7;
      llc_load_8xf4(gp + tid + 0 * 512, gp + tid + 1 * 512,
                    gp + tid + 2 * 512, gp + tid + 3 * 512,
                    gp + tid + 4 * 512, gp + tid + 5 * 512,
                    gp + tid + 6 * 512, gp + tid + 7 * 512,
                    v0, v1, v2, v3, v4, v5, v6, v7);
      SPLITW(v0, 0); SPLITW(v1, 1); SPLITW(v2, 2); SPLITW(v3, 3);
      SPLITW(v4, 4); SPLITW(v5, 5); SPLITW(v6, 6); SPLITW(v7, 7);
    }
    if (!IS_DEC) {  // stage x tile (cols 512..608, zeros past 592)
      for (int i = tid; i < 768; i += 512) {
        int row = i / 24, c4 = i % 24;
        float4 v = (c4 < 20)
            ? *(const float4*)(traj + (size_t)(r0 + row) * ROWSTRIDE +
                               (size_t)t * DDIM + c4 * 4)
            : make_float4(0.f, 0.f, 0.f, 0.f);
        int off = row * AST + 512 + c4 * 4;
        half4_t hi4, lo4;
        float f0 = v.x, f1 = v.y, f2 = v.z, f3 = v.w;
        f16 a = (f16)f0, b = (f16)f1, cc = (f16)f2, d = (f16)f3;
        hi4[0] = a; hi4[1] = b; hi4[2] = cc; hi4[3] = d;
        lo4[0] = (f16)(f0 - (float)a); lo4[1] = (f16)(f1 - (float)b);
        lo4[2] = (f16)(f2 - (float)cc); lo4[3] = (f16)(f3 - (float)d);
        *(half4_t*)&Ahi[off] = hi4; *(half4_t*)&Alo[off] = lo4;
      }
    }
    __syncthreads();

    // ---- gates: 4-term split-fp16 MFMA, full K per wave ----
    {
      float4_t acc0 = {breg, breg, breg, breg};
      float4_t acc1 = {0.f, 0.f, 0.f, 0.f};
      const int abase = (mt * 16 + l15) * AST + q * 8;
      #pragma unroll
      for (int kt = 0; kt < KT; kt++) {
        half8_t ahi = *(const half8_t*)&Ahi[abase + kt * 32];
        half8_t alo = *(const half8_t*)&Alo[abase + kt * 32];
        if (kt & 1) {
          acc1 = __builtin_amdgcn_mfma_f32_16x16x32_f16(ahi, Whi[kt], acc1, 0, 0, 0);
          acc1 = __builtin_amdgcn_mfma_f32_16x16x32_f16(alo, Whi[kt], acc1, 0, 0, 0);
          acc1 = __builtin_amdgcn_mfma_f32_16x16x32_f16(ahi, Wlo[kt], acc1, 0, 0, 0);
          acc1 = __builtin_amdgcn_mfma_f32_16x16x32_f16(alo, Wlo[kt], acc1, 0, 0, 0);
        } else {
          acc0 = __builtin_amdgcn_mfma_f32_16x16x32_f16(ahi, Whi[kt], acc0, 0, 0, 0);
          acc0 = __builtin_amdgcn_mfma_f32_16x16x32_f16(alo, Whi[kt], acc0, 0, 0, 0);
          acc0 = __builtin_amdgcn_mfma_f32_16x16x32_f16(ahi, Wlo[kt], acc0, 0, 0, 0);
          acc0 = __builtin_amdgcn_mfma_f32_16x16x32_f16(alo, Wlo[kt], acc0, 0, 0, 0);
        }
      }
      float4_t C = acc0 + acc1;
      #pragma unroll
      for (int i = 0; i < 4; i++)
        red[(mt * 16 + q * 4 + i) * 68 + nt * 16 + l15] = C[i];
    }
    // dec: fused y = fc(h_t) partials (k-split across waves)
    if (IS_DEC && jt < 5) {
      #pragma unroll
      for (int ym = 0; ym < 2; ym++) {
        float4_t ya = {0.f, 0.f, 0.f, 0.f};
        #pragma unroll
        for (int kk = 0; kk < 2; kk++) {
          const int kt = wv * 2 + kk;
          const int ao = (ym * 16 + l15) * AST + kt * 32 + q * 8;
          half8_t ahi = *(const half8_t*)&Ahi[ao];
          half8_t alo = *(const half8_t*)&Alo[ao];
          ya = __builtin_amdgcn_mfma_f32_16x16x32_f16(ahi, Fhi[kk], ya, 0, 0, 0);
          ya = __builtin_amdgcn_mfma_f32_16x16x32_f16(alo, Fhi[kk], ya, 0, 0, 0);
          ya = __builtin_amdgcn_mfma_f32_16x16x32_f16(ahi, Flo[kk], ya, 0, 0, 0);
          ya = __builtin_amdgcn_mfma_f32_16x16x32_f16(alo, Flo[kk], ya, 0, 0, 0);
        }
        #pragma unroll
        for (int i = 0; i < 4; i++)
          ypart[wv * 516 + (ym * 16 + q * 4 + i) * 16 + l15] = ya[i];
      }
    }
    __syncthreads();

    // ---- elementwise (c in VGPR), h -> LLC; y reduce -> recon ----
    {
      float ig = red[eb * 68 + ed];
      float fg = red[eb * 68 + 16 + ed];
      float gg = red[eb * 68 + 32 + ed];
      float og = red[eb * 68 + 48 + ed];
      float cn = sigmoidf_(fg) * c_reg + sigmoidf_(ig) * tanhf(gg);
      c_reg = cn;
      llc_store_f32(&hout[(size_t)(r0 + eb) * HDIM + d0 + ed],
                    sigmoidf_(og) * tanhf(cn));
    }
    if (IS_DEC && jt < 5) {
      float acc = ybias;
      #pragma unroll
      for (int w8 = 0; w8 < 8; w8++) acc += ypart[w8 * 516 + tid];
      recon[(size_t)(r0 + (tid >> 4)) * ROWSTRIDE + (size_t)(t - 1) * DDIM +
            jt * 16 + (tid & 15)] = acc;
    }
    wait_vm0();       // own h store is in LLC
    __syncthreads();  // whole block's h stores are in LLC

    // ---- group barrier: per-block flag store + lane-parallel poll ----
    if (IS_DEC || t < TT - 1) {
      const int done = t - t_begin + 1;
      if (tid == 0) llc_store_i32(&flags[rt * 32 + jt], done);
      if (tid < 64) {
        const int* fp = flags + rt * 32 + (tid & 31);
        while (llc_load_i32(fp) < done) __builtin_amdgcn_s_sleep(1);
      }
      __syncthreads();
    }
  }

  // ---- dec: recon col 255 = fc(h_256 = hA) ----
  if (IS_DEC) {
    if (jt >= 5) return;
    {
      const float4* gp = (const float4*)(hA + (size_t)r0 * HDIM);
      float4 v0, v1, v2, v3, v4, v5, v6, v7;
      llc_load_8xf4(gp + tid + 0 * 512, gp + tid + 1 * 512,
                    gp + tid + 2 * 512, gp + tid + 3 * 512,
                    gp + tid + 4 * 512, gp + tid + 5 * 512,
                    gp + tid + 6 * 512, gp + tid + 7 * 512,
                    v0, v1, v2, v3, v4, v5, v6, v7);
      SPLITW(v0, 0); SPLITW(v1, 1); SPLITW(v2, 2); SPLITW(v3, 3);
      SPLITW(v4, 4); SPLITW(v5, 5); SPLITW(v6, 6); SPLITW(v7, 7);
    }
    __syncthreads();
    #pragma unroll
    for (int ym = 0; ym < 2; ym++) {
      float4_t ya = {0.f, 0.f, 0.f, 0.f};
      #pragma unroll
      for (int kk = 0; kk < 2; kk++) {
        const int kt = wv * 2 + kk;
        const int ao = (ym * 16 + l15) * AST + kt * 32 + q * 8;
        half8_t ahi = *(const half8_t*)&Ahi[ao];
        half8_t alo = *(const half8_t*)&Alo[ao];
        ya = __builtin_amdgcn_mfma_f32_16x16x32_f16(ahi, Fhi[kk], ya, 0, 0, 0);
        ya = __builtin_amdgcn_mfma_f32_16x16x32_f16(alo, Fhi[kk], ya, 0, 0, 0);
        ya = __builtin_amdgcn_mfma_f32_16x16x32_f16(ahi, Flo[kk], ya, 0, 0, 0);
        ya = __builtin_amdgcn_mfma_f32_16x16x32_f16(alo, Flo[kk], ya, 0, 0, 0);
      }
      #pragma unroll
      for (int i = 0; i < 4; i++)
        ypart[wv * 516 + (ym * 16 + q * 4 + i) * 16 + l15] = ya[i];
    }
    __syncthreads();
    {
      float acc = ybias;
      #pragma unroll
      for (int w8 = 0; w8 < 8; w8++) acc += ypart[w8 * 516 + tid];
      recon[(size_t)(r0 + (tid >> 4)) * ROWSTRIDE + (size_t)255 * DDIM +
            jt * 16 + (tid & 15)] = acc;
    }
  }
  #undef SPLITW
}

// ---------------- vector quantizer ----------------------------------------------
__global__ __launch_bounds__(256) void vq_kernel(
    const float* __restrict__ z, const float* __restrict__ emb,
    float* __restrict__ quant, float* __restrict__ vq_part,
    float* __restrict__ out_idx) {
  __shared__ float sz[512];
  __shared__ float sd[256];
  __shared__ int si[256];
  int b = blockIdx.x, tid = threadIdx.x;
  sz[tid] = z[(size_t)b * HDIM + tid];
  sz[tid + 256] = z[(size_t)b * HDIM + 256 + tid];
  __syncthreads();
  float bd = 3.4e38f;
  int bk = 0;
  for (int k = tid; k < 512; k += 256) {
    const float4* e4 = (const float4*)(emb + (size_t)k * HDIM);
    const float4* z4 = (const float4*)sz;
    float dot = 0.f, ee = 0.f;
    #pragma unroll 4
    for (int qq = 0; qq < 128; qq++) {
      float4 ev = e4[qq], zv = z4[qq];
      dot += ev.x * zv.x + ev.y * zv.y + ev.z * zv.z + ev.w * zv.w;
      ee += ev.x * ev.x + ev.y * ev.y + ev.z * ev.z + ev.w * ev.w;
    }
    float dist = ee - 2.f * dot;
    if (dist < bd) { bd = dist; bk = k; }
  }
  sd[tid] = bd; si[tid] = bk;
  __syncthreads();
  for (int s = 128; s > 0; s >>= 1) {
    if (tid < s) {
      float od = sd[tid + s]; int ok = si[tid + s];
      if (od < sd[tid] || (od == sd[tid] && ok < si[tid])) { sd[tid] = od; si[tid] = ok; }
    }
    __syncthreads();
  }
  int kbest = si[0];
  __syncthreads();
  float e0 = emb[(size_t)kbest * HDIM + tid];
  float e1 = emb[(size_t)kbest * HDIM + 256 + tid];
  quant[(size_t)b * HDIM + tid] = e0;
  quant[(size_t)b * HDIM + 256 + tid] = e1;
  float q0 = e0 - sz[tid], q1 = e1 - sz[tid + 256];
  sd[tid] = q0 * q0 + q1 * q1;
  __syncthreads();
  for (int st = 128; st > 0; st >>= 1) {
    if (tid < st) sd[tid] += sd[tid + st];
    __syncthreads();
  }
  if (tid == 0) { vq_part[b] = sd[0]; out_idx[b] = (float)kbest; }
}

__global__ __launch_bounds__(256) void vq_reduce_kernel(const float* __restrict__ vq_part,
                                                        float* __restrict__ out_loss) {
  __shared__ float s[256];
  int tid = threadIdx.x;
  s[tid] = vq_part[tid];
  __syncthreads();
  for (int st = 128; st > 0; st >>= 1) {
    if (tid < st) s[tid] += s[tid + st];
    __syncthreads();
  }
  if (tid == 0) out_loss[0] = s[0] * 1.25f / (float)(BB * HDIM);
}

extern "C" void kernel_launch(void* const* d_in, const int* in_sizes, int n_in,
                              void* d_out, int out_size, void* d_ws, size_t ws_size,
                              hipStream_t stream) {
  const float* traj = (const float*)d_in[0];
  const float* eWih = (const float*)d_in[2];
  const float* eWhh = (const float*)d_in[3];
  const float* eb1  = (const float*)d_in[4];
  const float* eb2  = (const float*)d_in[5];
  const float* emb  = (const float*)d_in[6];
  const float* dWih = (const float*)d_in[7];
  const float* dWhh = (const float*)d_in[8];
  const float* db1  = (const float*)d_in[9];
  const float* db2  = (const float*)d_in[10];
  const float* fcW  = (const float*)d_in[11];
  const float* fcb  = (const float*)d_in[12];

  float* out = (float*)d_out;
  float* recon = out;
  float* out_loss = out + 5242880;
  float* out_idx = out + 5242881;

  float* ws = (float*)d_ws;
  float* hA      = ws + WS_HA;
  float* cD      = ws + WS_CD;
  int*   bar     = (int*)(ws + WS_BAR);
  float* hB      = ws + WS_HB;
  float* quant   = ws + WS_QUANT;
  float* vq_part = ws + WS_VQP;
  float* b_enc   = ws + WS_BENC;
  float* b_dec0  = ws + WS_BDEC0;
  float* b_eff   = ws + WS_BEFF;
  float* W_eff   = ws + WS_WEFF;

  // zero hA, cD, flags
  zero_kernel<<<257, 256, 0, stream>>>((float4*)ws, 65792);
  bias_init_kernel<<<8, 256, 0, stream>>>(eb1, eb2, db1, db2, dWih, fcb,
                                          b_enc, b_dec0, b_eff);
  fold_kernel<<<2048, 256, 0, stream>>>(dWih, dWhh, fcW, W_eff);

  // encoder: t=0..255 persistent; z lands in hA
  lstm_persist<0><<<256, 512, 0, stream>>>(
      eWhh, eWih, b_enc, traj, nullptr, nullptr, nullptr, nullptr, hA, hB, bar);

  vq_kernel<<<256, 256, 0, stream>>>(hA, emb, quant, vq_part, out_idx);
  vq_reduce_kernel<<<1, 256, 0, stream>>>(vq_part, out_loss);

  // decoder t=0 (plain dWhh, x=0): h_1 -> hB, c_1 -> cD
  lstm_step_kernel<<<512, 256, 0, stream>>>(dWhh, b_dec0, quant, cD, hB);
  // decoder t=1..255 persistent with W_eff; recon fused
  lstm_persist<1><<<256, 512, 0, stream>>>(
      W_eff, nullptr, b_eff, nullptr, cD, fcW, fcb, recon, hA, hB, bar + 256);
}